// Round 11
// baseline (192.592 us; speedup 1.0000x reference)
//
#include <hip/hip_runtime.h>
#include <hip/hip_bf16.h>

// GCN 2-layer: N=50000 nodes, E=800000 edges, 256 -> 64 (relu) -> 40 (log_softmax)
// Gather model (R0-R6): per-row-touch rate ~20k/us invariant -> parked (~80us).
// R10 (-16.5): LDS counting sort replaced atomic-return hist. R11: the binned
// SCATTER (800k random 4B writes) is itself gather-class (~20k touches/us):
//  (a) bin role: LDS-local sort -> contiguous per-bucket burst writes (~150k);
//  (b) k_rankfill fuses rankscan+fill: one binned read, LDS rank+scan
//      (partial == bcur), csr staged in LDS -> coalesced write; rank8b gone;
//  (c) h1r f32 dropped: gemm writes unscaled bf16 h1u, k_scale rescales
//      in place (32MB -> 13MB traffic; +<=1ulp bf16 double-round).
// Gathers = R8 verbatim (controls). 6 launches.

constexpr int NN   = 50000;
constexpr int NNP  = 50048;                 // padded row count (zero rows >= NN)
constexpr int ZR   = 50000;                 // zero-row index for padding lanes
constexpr int NE   = 800000;
constexpr int FEAT = 256;
constexpr int HID  = 64;
constexpr int OUTD = 40;
constexpr int NC   = (NN + 255) / 256;      // 196 chunks == buckets
constexpr int NBUK = NC;
constexpr int MAXB = 4608;                  // bucket cap (mean 4082, +8sigma)
constexpr int RPT  = MAXB / 256;            // 18 records/thread max in rankfill
constexpr int FCH  = 2048;                  // bin: edges per chunk
constexpr int NCH  = (NE + FCH - 1) / FCH;  // 391 chunks
constexpr int GB   = NNP / 64;              // 782 gemm blocks

typedef short bf16x8 __attribute__((ext_vector_type(8)));
typedef float f32x4  __attribute__((ext_vector_type(4)));
typedef float f32x2  __attribute__((ext_vector_type(2)));

__device__ __forceinline__ float b2f(__hip_bfloat16 v) { return __bfloat162float(v); }
__device__ __forceinline__ float bflo(unsigned u) { return __uint_as_float(u << 16); }
__device__ __forceinline__ float bfhi(unsigned u) { return __uint_as_float(u & 0xffff0000u); }
__device__ __forceinline__ unsigned short f2bu(float f) {
    __hip_bfloat16 h = __float2bfloat16(f);
    return *(unsigned short*)&h;
}
__device__ __forceinline__ unsigned pack2bf(float a, float b) {
    return (unsigned)f2bu(a) | ((unsigned)f2bu(b) << 16);
}
__device__ __forceinline__ float loadF(const void* p, int i, bool f32) {
    return f32 ? ((const float*)p)[i] : b2f(((const __hip_bfloat16*)p)[i]);
}
__device__ __forceinline__ int loadE(const int* ei, int e, int row, bool i64) {
    long long idx = (long long)row * NE + e;
    return i64 ? ei[2 * idx] : ei[idx];
}
__device__ __forceinline__ bf16x8 pack8(float4 a, float4 b) {
    bf16x8 r;
    r[0] = (short)f2bu(a.x); r[1] = (short)f2bu(a.y);
    r[2] = (short)f2bu(a.z); r[3] = (short)f2bu(a.w);
    r[4] = (short)f2bu(b.x); r[5] = (short)f2bu(b.y);
    r[6] = (short)f2bu(b.z); r[7] = (short)f2bu(b.w);
    return r;
}

// ---- fp8 e4m3 (OCP) pack/unpack: HW cvt if available, exact SW fallback ----
#if __has_builtin(__builtin_amdgcn_cvt_pk_f32_fp8) && __has_builtin(__builtin_amdgcn_cvt_pk_fp8_f32)
__device__ __forceinline__ void unpack_fp8x4(unsigned u, float& f0, float& f1,
                                             float& f2, float& f3) {
    f32x2 lo = __builtin_amdgcn_cvt_pk_f32_fp8((int)u, false);
    f32x2 hi = __builtin_amdgcn_cvt_pk_f32_fp8((int)u, true);
    f0 = lo[0]; f1 = lo[1]; f2 = hi[0]; f3 = hi[1];
}
__device__ __forceinline__ unsigned pack_fp8x4(float a, float b, float c, float d) {
    int v = 0;
    v = __builtin_amdgcn_cvt_pk_fp8_f32(a, b, v, false);
    v = __builtin_amdgcn_cvt_pk_fp8_f32(c, d, v, true);
    return (unsigned)v;
}
#else
__device__ __forceinline__ float dec8(unsigned b) {
    return __uint_as_float(((b & 0x80u) << 24) | ((b & 0x7fu) << 20)) * 0x1p120f;
}
__device__ __forceinline__ void unpack_fp8x4(unsigned u, float& f0, float& f1,
                                             float& f2, float& f3) {
    f0 = dec8(u & 0xff); f1 = dec8((u >> 8) & 0xff);
    f2 = dec8((u >> 16) & 0xff); f3 = dec8(u >> 24);
}
__device__ __forceinline__ unsigned enc8(float f) {
    float a = fabsf(f) * 0x1p-120f;
    unsigned ub = __float_as_uint(a);
    unsigned lsb = (ub >> 20) & 1u;
    ub += 0x7FFFFu + lsb;                       // RNE into 3-bit mantissa
    unsigned v = (ub >> 20) & 0x7fu;
    if (v > 0x7e) v = 0x7e;
    return v | ((__float_as_uint(f) >> 24) & 0x80u);
}
__device__ __forceinline__ unsigned pack_fp8x4(float a, float b, float c, float d) {
    return enc8(a) | (enc8(b) << 8) | (enc8(c) << 16) | (enc8(d) << 24);
}
#endif

// ---- zero cursors + dtype detection (wave-parallel) + h2 pad-row zero ------
__global__ __launch_bounds__(256) void k_zero(const unsigned* __restrict__ xw,
                                              const int* __restrict__ ew,
                                              int* flags, int* bcur,
                                              unsigned* __restrict__ h2pad) {
    const int t = threadIdx.x;
    bcur[t] = 0;                               // 256 cursors (196 used)
    if (t < 16) h2pad[t] = 0;                  // fp8 zero row
    if (t < 64) {
        int outliers = 0;
#pragma unroll
        for (int k = t; k < 256; k += 64) {
            int e = (xw[k] >> 7) & 0xFF;       // exponent of low bf16 half
            if (e < 100 || e > 140) outliers++;
        }
        int nz = 0;
        if (t < 32) nz = (ew[1 + 2 * t] != 0) ? 1 : 0;
#pragma unroll
        for (int off = 32; off; off >>= 1) {
            outliers += __shfl_down(outliers, off, 64);
            nz       += __shfl_down(nz, off, 64);
        }
        if (t == 0) {
            flags[0] = (outliers > 64) ? 1 : 0;
            flags[1] = (nz == 0) ? 1 : 0;
        }
    }
}

// ---- bin (blocks [0,NCH)) || gemm-unscaled-bf16 (blocks [NCH,NCH+GB)) ------
// bin: LDS hist + local rank, LDS-local sort by bucket, per-bucket burst
// write to bucket regions (contiguous). gemm: h1u = bf16(x @ W1), no dinv.
__global__ __launch_bounds__(256) void k_bingemm(const int* __restrict__ ei,
                                                 const int* __restrict__ flags,
                                                 int* __restrict__ bcur,
                                                 unsigned* __restrict__ binned,
                                                 const void* __restrict__ xb,
                                                 const void* __restrict__ W1,
                                                 unsigned short* __restrict__ h1u) {
    __shared__ __align__(16) unsigned char smem[64 * 264 * 2];   // 33792 B union
    const bool f32 = flags[0] != 0;
    const int t = threadIdx.x;

    if (blockIdx.x < NCH) {
        const bool i64 = flags[1] != 0;
        int* histL = (int*)smem;                   // [256]
        int* lbase = histL + 256;                  // [256]
        unsigned* recL = (unsigned*)(lbase + 256); // [FCH]
        histL[t] = 0;
        __syncthreads();
        int dk[8], sk[8], lk[8];
        const int e0 = blockIdx.x * FCH;
#pragma unroll
        for (int k = 0; k < 8; k++) {
            int e = e0 + k * 256 + t;
            if (e < NE) {
                dk[k] = loadE(ei, e, 1, i64);
                sk[k] = loadE(ei, e, 0, i64);
                lk[k] = atomicAdd(&histL[dk[k] >> 8], 1);
            } else {
                dk[k] = -1;
            }
        }
        __syncthreads();
        const int v = histL[t];
        lbase[t] = v;
        __syncthreads();
        for (int off = 1; off < 256; off <<= 1) {
            int tmp = (t >= off) ? lbase[t - off] : 0;
            __syncthreads();
            lbase[t] += tmp;
            __syncthreads();
        }
        int excl = lbase[t] - v;
        __syncthreads();
        lbase[t] = excl;
        __syncthreads();
#pragma unroll
        for (int k = 0; k < 8; k++) {
            if (dk[k] >= 0) {
                int b = dk[k] >> 8;
                recL[lbase[b] + lk[k]] = (unsigned)(sk[k] | ((dk[k] & 0xff) << 16));
            }
        }
        int gbase = (v > 0) ? atomicAdd(&bcur[t], v) : 0;
        __syncthreads();
        const int lb = lbase[t];
        for (int i = 0; i < v; i++) {              // contiguous burst, bucket t
            int off = gbase + i;
            if (off < MAXB) binned[t * MAXB + off] = recL[lb + i];
        }
        return;
    }

    // ---------------- gemm role (bf16 output, unscaled) ----------------
    const int bid = blockIdx.x - NCH;              // 0..GB-1
    unsigned short* wt16 = (unsigned short*)smem;
    if (f32) {
        const float* wf = (const float*)W1;
        for (int i = t * 4; i < FEAT * HID; i += 1024) {
            float4 w = *(const float4*)(wf + i);
            int k = i >> 6, n0 = i & 63;
            wt16[(n0 + 0) * 264 + k] = f2bu(w.x);
            wt16[(n0 + 1) * 264 + k] = f2bu(w.y);
            wt16[(n0 + 2) * 264 + k] = f2bu(w.z);
            wt16[(n0 + 3) * 264 + k] = f2bu(w.w);
        }
    } else {
        const unsigned short* wu = (const unsigned short*)W1;
        for (int i = t * 4; i < FEAT * HID; i += 1024) {
            ushort4 w = *(const ushort4*)(wu + i);
            int k = i >> 6, n0 = i & 63;
            wt16[(n0 + 0) * 264 + k] = w.x;
            wt16[(n0 + 1) * 264 + k] = w.y;
            wt16[(n0 + 2) * 264 + k] = w.z;
            wt16[(n0 + 3) * 264 + k] = w.w;
        }
    }
    const int wv = t >> 6, lane = t & 63, l15 = lane & 15, quad = lane >> 4;
    const int gr = bid * 64 + wv * 16 + l15;
    const bool rowok = gr < NN;
    f32x4 acc[4];
#pragma unroll
    for (int nt = 0; nt < 4; nt++) acc[nt] = (f32x4){0.f, 0.f, 0.f, 0.f};
    __syncthreads();

    if (f32) {
        const float* xr = (const float*)xb + (size_t)gr * FEAT + quad * 8;
        float4 z4 = make_float4(0, 0, 0, 0);
        float4 c0 = rowok ? *(const float4*)xr : z4;
        float4 c1 = rowok ? *(const float4*)(xr + 4) : z4;
#pragma unroll
        for (int ks = 0; ks < 8; ks++) {
            float4 n0 = z4, n1 = z4;
            if (ks < 7 && rowok) {
                n0 = *(const float4*)(xr + (ks + 1) * 32);
                n1 = *(const float4*)(xr + (ks + 1) * 32 + 4);
            }
            bf16x8 a = pack8(c0, c1);
            const unsigned short* wk = wt16 + ks * 32 + quad * 8;
#pragma unroll
            for (int nt = 0; nt < 4; nt++) {
                bf16x8 b = *(const bf16x8*)(wk + (size_t)(nt * 16 + l15) * 264);
                acc[nt] = __builtin_amdgcn_mfma_f32_16x16x32_bf16(a, b, acc[nt], 0, 0, 0);
            }
            c0 = n0; c1 = n1;
        }
    } else {
        const unsigned short* xr = (const unsigned short*)xb + (size_t)gr * FEAT + quad * 8;
        bf16x8 zz = (bf16x8){0, 0, 0, 0, 0, 0, 0, 0};
        bf16x8 cur = rowok ? *(const bf16x8*)xr : zz;
#pragma unroll
        for (int ks = 0; ks < 8; ks++) {
            bf16x8 nxt = zz;
            if (ks < 7 && rowok) nxt = *(const bf16x8*)(xr + (ks + 1) * 32);
            const unsigned short* wk = wt16 + ks * 32 + quad * 8;
#pragma unroll
            for (int nt = 0; nt < 4; nt++) {
                bf16x8 b = *(const bf16x8*)(wk + (size_t)(nt * 16 + l15) * 264);
                acc[nt] = __builtin_amdgcn_mfma_f32_16x16x32_bf16(cur, b, acc[nt], 0, 0, 0);
            }
            cur = nxt;
        }
    }
    const int rbase = bid * 64 + wv * 16 + quad * 4;
#pragma unroll
    for (int r = 0; r < 4; r++) {
        int grow = rbase + r;   // < NNP always
#pragma unroll
        for (int nt = 0; nt < 4; nt++)
            h1u[(size_t)grow * HID + nt * 16 + l15] = f2bu(acc[nt][r]);
    }
}

// ---- fused rank + cnt/dinv/row_start + csr fill (one block per bucket) -----
// partial == bcur; csr region staged in LDS, written coalesced.
__global__ __launch_bounds__(256) void k_rankfill(const int* __restrict__ bcur,
                                                  const unsigned* __restrict__ binned,
                                                  int* __restrict__ pp,
                                                  int* __restrict__ cnt,
                                                  float* __restrict__ dinv,
                                                  int* __restrict__ row_start,
                                                  unsigned short* __restrict__ csr16) {
    __shared__ int h[256];
    __shared__ int s[256];
    __shared__ int ppL[256];
    __shared__ unsigned short csrL[MAXB];      // 9216 B
    const int t = threadIdx.x, b = blockIdx.x;
    h[t] = 0;
    __syncthreads();
    const int cntb = min(bcur[b], MAXB);
    const int base = b * MAXB;
    unsigned recA[RPT];
    int rkA[RPT];
#pragma unroll
    for (int j = 0; j < RPT; j++) {
        int pos = j * 256 + t;
        if (pos < cntb) {
            unsigned rec = binned[base + pos];
            recA[j] = rec;
            rkA[j] = atomicAdd(&h[(rec >> 16) & 0xff], 1);
        }
    }
    __syncthreads();
    // cross-bucket pp scan (partial == clamped bcur)
    int pv = (t < NC) ? min(bcur[t], MAXB) : 0;
    ppL[t] = pv;
    __syncthreads();
    for (int off = 1; off < 256; off <<= 1) {
        int tmp = (t >= off) ? ppL[t - off] : 0;
        __syncthreads();
        ppL[t] += tmp;
        __syncthreads();
    }
    int pexcl = ppL[t] - pv;
    __syncthreads();
    ppL[t] = pexcl;
    __syncthreads();
    if (b == 0) pp[t] = pexcl;
    // node-level: cnt, dinv, local row_start scan
    const int i = b * 256 + t;
    const int v = h[t];
    if (i < NN) {
        cnt[i] = v;
        dinv[i] = rsqrtf(1.0f + (float)v);     // +1 self loop
    }
    s[t] = v;
    __syncthreads();
    for (int off = 1; off < 256; off <<= 1) {
        int tmp = (t >= off) ? s[t - off] : 0;
        __syncthreads();
        s[t] += tmp;
        __syncthreads();
    }
    int excl = s[t] - v;
    if (i < NN) row_start[i] = excl;           // exclusive within chunk
    __syncthreads();
    s[t] = excl;
    __syncthreads();
    // place records into LDS csr, then stream out coalesced
#pragma unroll
    for (int j = 0; j < RPT; j++) {
        int pos = j * 256 + t;
        if (pos < cntb) {
            int lo = (recA[j] >> 16) & 0xff;
            csrL[s[lo] + rkA[j]] = (unsigned short)(recA[j] & 0xffff);
        }
    }
    __syncthreads();
    const int ppb = ppL[b];
    for (int pos = t; pos < cntb; pos += 256)
        csr16[ppb + pos] = csrL[pos];
}

// ---- in-place h1 scale: h1u = bf16(bf16(x@W1) * dinv[row]) -----------------
__global__ __launch_bounds__(256) void k_scale(const float* __restrict__ dinv,
                                               unsigned* __restrict__ h1q) {
    const int stride = gridDim.x * 256;
    for (int i = blockIdx.x * 256 + threadIdx.x; i < NNP * 32; i += stride) {
        unsigned u = h1q[i];                   // 2 bf16
        int row = i >> 5;
        float dv = (row < NN) ? dinv[row] : 0.f;
        h1q[i] = pack2bf(bflo(u) * dv, bfhi(u) * dv);
    }
}

// ---- fused: s = sum h1'[{n}uN(n)] ; g = relu(dn*s + b1) ; h2' = dn*(g@W2) --
// R8 verbatim. h2 OUTPUT fp8 e4m3, 16-dword rows.
__global__ __launch_bounds__(256, 4) void k_gather1f(const uint2* __restrict__ h1v,
                                                  const float* __restrict__ dinv,
                                                  const int* __restrict__ row_start,
                                                  const int* __restrict__ pp,
                                                  const int* __restrict__ cnt,
                                                  const unsigned short* __restrict__ csr16,
                                                  const void* __restrict__ W2,
                                                  const void* __restrict__ b1,
                                                  const int* __restrict__ flags,
                                                  unsigned* __restrict__ h2f) {
    __shared__ __align__(16) float w2t[OUTD * 68];   // [col][k], stride 68
    __shared__ __align__(16) float gbuf[16 * 68];    // [node][k], stride 68
    __shared__ __align__(16) float obuf[16][40];     // [node][col] f32 pre-pack
    __shared__ float dns[16];
    const bool f32 = flags[0] != 0;
    const int t = threadIdx.x;
    for (int i = t; i < HID * OUTD; i += 256) {
        int c = i >> 6, k = i & 63;
        w2t[c * 68 + k] = loadF(W2, (size_t)k * OUTD + c, f32);
    }
    const int nl = t >> 4, l16 = t & 15;
    const int n = blockIdx.x * 16 + nl;      // < NN (grid exact)
    const float dn = dinv[n];
    uint2 u0 = h1v[n * 16 + l16];            // fits int: < 800016
    float a0 = bflo(u0.x), a1 = bfhi(u0.x), a2 = bflo(u0.y), a3 = bfhi(u0.y);
    float e0 = 0.f, e1 = 0.f, e2 = 0.f, e3 = 0.f;
    const int rs = row_start[n] + pp[n >> 8], c = cnt[n];
    for (int base = 0; base < c; base += 16) {
        int rem = c - base;
        int sv = (l16 < rem) ? (int)csr16[rs + base + l16] : ZR;
        uint2 b[8], d[8];
#pragma unroll
        for (int j = 0; j < 8; j++) {
            int s = __shfl(sv, j, 16);
            b[j] = h1v[(s << 4) | l16];
        }
#pragma unroll
        for (int j = 0; j < 8; j++) {
            int s = __shfl(sv, j + 8, 16);
            d[j] = h1v[(s << 4) | l16];
        }
#pragma unroll
        for (int j = 0; j < 8; j++) {
            a0 += bflo(b[j].x); a1 += bfhi(b[j].x);
            a2 += bflo(b[j].y); a3 += bfhi(b[j].y);
            e0 += bflo(d[j].x); e1 += bfhi(d[j].x);
            e2 += bflo(d[j].y); e3 += bfhi(d[j].y);
        }
    }
    int cb = 4 * l16;
    float g0 = fmaxf(dn * (a0 + e0) + loadF(b1, cb, f32), 0.f);
    float g1 = fmaxf(dn * (a1 + e1) + loadF(b1, cb + 1, f32), 0.f);
    float g2 = fmaxf(dn * (a2 + e2) + loadF(b1, cb + 2, f32), 0.f);
    float g3 = fmaxf(dn * (a3 + e3) + loadF(b1, cb + 3, f32), 0.f);
    *(float4*)(gbuf + nl * 68 + cb) = make_float4(g0, g1, g2, g3);
    if (l16 == 0) dns[nl] = dn;
    __syncthreads();
    for (int idx = t; idx < 16 * OUTD; idx += 256) {
        int node = idx / OUTD, col = idx % OUTD;
        const float4* gp = (const float4*)(gbuf + node * 68);
        const float4* wp = (const float4*)(w2t + col * 68);
        float o = 0.f;
#pragma unroll 4
        for (int k4 = 0; k4 < 16; k4++) {
            float4 a = gp[k4], b = wp[k4];
            o += a.x * b.x + a.y * b.y + a.z * b.z + a.w * b.w;
        }
        obuf[node][col] = o * dns[node];
    }
    __syncthreads();
    if (t < 160) {
        int node = t / 10, dw = t % 10;
        const float* op = obuf[node] + dw * 4;
        h2f[(blockIdx.x * 16 + node) * 16 + dw] =
            pack_fp8x4(op[0], op[1], op[2], op[3]);
    }
}

// ---- CSR gather layer 2 (fp8 h2, 1 line/row) + bias + log_softmax ----------
// R8 verbatim.
__global__ __launch_bounds__(256, 4) void k_gather2(const unsigned* __restrict__ h2f,
                                                 const float* __restrict__ dinv,
                                                 const int* __restrict__ row_start,
                                                 const int* __restrict__ pp,
                                                 const int* __restrict__ cnt,
                                                 const unsigned short* __restrict__ csr16,
                                                 const void* __restrict__ b2,
                                                 const int* __restrict__ flags,
                                                 void* __restrict__ out) {
    const bool f32 = flags[0] != 0;
    const int t = threadIdx.x;
    const int nl = t >> 4, l16 = t & 15;
    const int n = blockIdx.x * 16 + nl;      // < NN (grid exact)
    const bool act = l16 < 10;               // 10 dwords (40 fp8 cols) per row
    const float dn = dinv[n];
    const int lclamp = act ? l16 : 9;        // inactive lanes read lane-9 slot (discarded)
    float a0, a1, a2, a3;
    unpack_fp8x4(h2f[n * 16 + lclamp], a0, a1, a2, a3);   // self row
    float e0 = 0.f, e1 = 0.f, e2 = 0.f, e3 = 0.f;
    const int rs = row_start[n] + pp[n >> 8], c = cnt[n];
    for (int base = 0; base < c; base += 16) {
        int rem = c - base;
        int sv = (l16 < rem) ? (int)csr16[rs + base + l16] : ZR;
        unsigned b[8], d[8];
#pragma unroll
        for (int j = 0; j < 8; j++) {
            int s = __shfl(sv, j, 16);
            b[j] = h2f[(s << 4) + lclamp];
        }
#pragma unroll
        for (int j = 0; j < 8; j++) {
            int s = __shfl(sv, j + 8, 16);
            d[j] = h2f[(s << 4) + lclamp];
        }
#pragma unroll
        for (int j = 0; j < 8; j++) {
            float x0, x1, x2, x3, y0, y1, y2, y3;
            unpack_fp8x4(b[j], x0, x1, x2, x3);
            unpack_fp8x4(d[j], y0, y1, y2, y3);
            a0 += x0; a1 += x1; a2 += x2; a3 += x3;
            e0 += y0; e1 += y1; e2 += y2; e3 += y3;
        }
    }
    int cb = 4 * l16;
    float v0 = -3.0e38f, v1 = -3.0e38f, v2 = -3.0e38f, v3 = -3.0e38f;
    if (act) {
        v0 = dn * (a0 + e0) + loadF(b2, cb, f32);
        v1 = dn * (a1 + e1) + loadF(b2, cb + 1, f32);
        v2 = dn * (a2 + e2) + loadF(b2, cb + 2, f32);
        v3 = dn * (a3 + e3) + loadF(b2, cb + 3, f32);
    }
    float mx = fmaxf(fmaxf(v0, v1), fmaxf(v2, v3));
#pragma unroll
    for (int off = 8; off; off >>= 1) mx = fmaxf(mx, __shfl_xor(mx, off, 16));
    float ev = act ? expf(v0 - mx) + expf(v1 - mx) + expf(v2 - mx) + expf(v3 - mx) : 0.f;
#pragma unroll
    for (int off = 8; off; off >>= 1) ev += __shfl_xor(ev, off, 16);
    float lg = logf(ev);
    if (act) {
        float r0 = v0 - mx - lg, r1 = v1 - mx - lg;
        float r2 = v2 - mx - lg, r3 = v3 - mx - lg;
        if (f32) {
            *(float4*)((float*)out + (size_t)n * OUTD + cb) = make_float4(r0, r1, r2, r3);
        } else {
            ((uint2*)out)[(size_t)n * 10 + l16] = make_uint2(pack2bf(r0, r1), pack2bf(r2, r3));
        }
    }
}

extern "C" void kernel_launch(void* const* d_in, const int* in_sizes, int n_in,
                              void* d_out, int out_size, void* d_ws, size_t ws_size,
                              hipStream_t stream) {
    const void* x  = d_in[0];
    const int*  ei = (const int*)d_in[1];
    const void* W1 = d_in[2];
    const void* b1 = d_in[3];
    const void* W2 = d_in[4];
    const void* b2 = d_in[5];

    // ws layout (4-byte words):
    // flags[16] | dinv[50048] | cnt[50048] | row_start[50048] | pp[256] |
    // bcur[256] | binned uint[196*4608] | csr16 ushort[800000] |
    // h1u bf16[NNP*64] | h2f uint[NNP*16]   (~16 MB)
    float* ws        = (float*)d_ws;
    int*   flags     = (int*)ws;
    float* dinv      = ws + 16;
    int*   cnt       = (int*)(dinv + 50048);
    int*   row_start = cnt + 50048;
    int*   pp        = row_start + 50048;
    int*   bcur      = pp + 256;                                  // 256
    unsigned* binned = (unsigned*)(bcur + 256);                   // 196*4608
    unsigned short* csr16 = (unsigned short*)(binned + NBUK * MAXB);
    unsigned short* h1u   = csr16 + NE;                           // NNP*64 bf16
    unsigned* h2f = (unsigned*)(h1u + (size_t)NNP * HID);         // NNP*16 dw
    unsigned* h2pad = h2f + (size_t)ZR * 16;                      // 16 dwords

    k_zero    <<<1, 256, 0, stream>>>((const unsigned*)x, ei, flags, bcur, h2pad);
    k_bingemm <<<NCH + GB, 256, 0, stream>>>(ei, flags, bcur, binned, x, W1, h1u);
    k_rankfill<<<NBUK, 256, 0, stream>>>(bcur, binned, pp, cnt, dinv, row_start, csr16);
    k_scale   <<<512, 256, 0, stream>>>(dinv, (unsigned*)h1u);
    k_gather1f<<<NN / 16, 256, 0, stream>>>((const uint2*)h1u, dinv, row_start, pp, cnt,
                                            csr16, W2, b1, flags, h2f);
    k_gather2 <<<NN / 16, 256, 0, stream>>>(h2f, dinv, row_start, pp, cnt, csr16,
                                            b2, flags, d_out);
}

// Round 12
// 190.521 us; speedup vs baseline: 1.0109x; 1.0109x over previous
//
#include <hip/hip_runtime.h>
#include <hip/hip_bf16.h>

// GCN 2-layer: N=50000 nodes, E=800000 edges, 256 -> 64 (relu) -> 40 (log_softmax)
// Gather model (R0-R6): per-row-touch rate ~20k/us invariant -> parked (~80us).
// R11 null: the "burst" bin write was still 64-lines-per-store (thread t ->
// region t*18KB). R12: (a) bucket-tagged records written by POSITION ->
// truly coalesced (~150k write line-touches); (b) 6 -> 5 dispatches:
// k_zero folded into bingemm (per-block wave-0 dtype detect) + 1KB memset
// for bcur; k_scale folded into rankfillscale (each block scales its own
// 256 nodes' h1 rows using LDS degrees). Gathers = R8 verbatim (controls).

constexpr int NN   = 50000;
constexpr int NNP  = 50048;                 // padded row count (zero rows >= NN)
constexpr int ZR   = 50000;                 // zero-row index for padding lanes
constexpr int NE   = 800000;
constexpr int FEAT = 256;
constexpr int HID  = 64;
constexpr int OUTD = 40;
constexpr int NC   = (NN + 255) / 256;      // 196 chunks == buckets
constexpr int NBUK = NC;
constexpr int MAXB = 4608;                  // bucket cap (mean 4082, +8sigma)
constexpr int RPT  = MAXB / 256;            // 18 records/thread max in rankfill
constexpr int FCH  = 2048;                  // bin: edges per chunk
constexpr int NCH  = (NE + FCH - 1) / FCH;  // 391 chunks
constexpr int GB   = NNP / 64;              // 782 gemm blocks

typedef short bf16x8 __attribute__((ext_vector_type(8)));
typedef float f32x4  __attribute__((ext_vector_type(4)));
typedef float f32x2  __attribute__((ext_vector_type(2)));

__device__ __forceinline__ float b2f(__hip_bfloat16 v) { return __bfloat162float(v); }
__device__ __forceinline__ float bflo(unsigned u) { return __uint_as_float(u << 16); }
__device__ __forceinline__ float bfhi(unsigned u) { return __uint_as_float(u & 0xffff0000u); }
__device__ __forceinline__ unsigned short f2bu(float f) {
    __hip_bfloat16 h = __float2bfloat16(f);
    return *(unsigned short*)&h;
}
__device__ __forceinline__ unsigned pack2bf(float a, float b) {
    return (unsigned)f2bu(a) | ((unsigned)f2bu(b) << 16);
}
__device__ __forceinline__ float loadF(const void* p, int i, bool f32) {
    return f32 ? ((const float*)p)[i] : b2f(((const __hip_bfloat16*)p)[i]);
}
__device__ __forceinline__ int loadE(const int* ei, int e, int row, bool i64) {
    long long idx = (long long)row * NE + e;
    return i64 ? ei[2 * idx] : ei[idx];
}
__device__ __forceinline__ bf16x8 pack8(float4 a, float4 b) {
    bf16x8 r;
    r[0] = (short)f2bu(a.x); r[1] = (short)f2bu(a.y);
    r[2] = (short)f2bu(a.z); r[3] = (short)f2bu(a.w);
    r[4] = (short)f2bu(b.x); r[5] = (short)f2bu(b.y);
    r[6] = (short)f2bu(b.z); r[7] = (short)f2bu(b.w);
    return r;
}

// ---- fp8 e4m3 (OCP) pack/unpack: HW cvt if available, exact SW fallback ----
#if __has_builtin(__builtin_amdgcn_cvt_pk_f32_fp8) && __has_builtin(__builtin_amdgcn_cvt_pk_fp8_f32)
__device__ __forceinline__ void unpack_fp8x4(unsigned u, float& f0, float& f1,
                                             float& f2, float& f3) {
    f32x2 lo = __builtin_amdgcn_cvt_pk_f32_fp8((int)u, false);
    f32x2 hi = __builtin_amdgcn_cvt_pk_f32_fp8((int)u, true);
    f0 = lo[0]; f1 = lo[1]; f2 = hi[0]; f3 = hi[1];
}
__device__ __forceinline__ unsigned pack_fp8x4(float a, float b, float c, float d) {
    int v = 0;
    v = __builtin_amdgcn_cvt_pk_fp8_f32(a, b, v, false);
    v = __builtin_amdgcn_cvt_pk_fp8_f32(c, d, v, true);
    return (unsigned)v;
}
#else
__device__ __forceinline__ float dec8(unsigned b) {
    return __uint_as_float(((b & 0x80u) << 24) | ((b & 0x7fu) << 20)) * 0x1p120f;
}
__device__ __forceinline__ void unpack_fp8x4(unsigned u, float& f0, float& f1,
                                             float& f2, float& f3) {
    f0 = dec8(u & 0xff); f1 = dec8((u >> 8) & 0xff);
    f2 = dec8((u >> 16) & 0xff); f3 = dec8(u >> 24);
}
__device__ __forceinline__ unsigned enc8(float f) {
    float a = fabsf(f) * 0x1p-120f;
    unsigned ub = __float_as_uint(a);
    unsigned lsb = (ub >> 20) & 1u;
    ub += 0x7FFFFu + lsb;                       // RNE into 3-bit mantissa
    unsigned v = (ub >> 20) & 0x7fu;
    if (v > 0x7e) v = 0x7e;
    return v | ((__float_as_uint(f) >> 24) & 0x80u);
}
__device__ __forceinline__ unsigned pack_fp8x4(float a, float b, float c, float d) {
    return enc8(a) | (enc8(b) << 8) | (enc8(c) << 16) | (enc8(d) << 24);
}
#endif

// ---- bin (blocks [0,NCH)) || gemm-unscaled-bf16 (blocks [NCH,NCH+GB)) ------
// Per-block wave-0 dtype detection (block 0 publishes flags). Bin: LDS hist +
// local rank, bucket-tagged records placed sorted in LDS, POSITION-ordered
// coalesced write-out. gemm: h1u = bf16(x @ W1), unscaled.
__global__ __launch_bounds__(256) void k_bingemm(const int* __restrict__ ei,
                                                 const unsigned* __restrict__ xw,
                                                 int* __restrict__ flags,
                                                 int* __restrict__ bcur,
                                                 unsigned* __restrict__ binned,
                                                 const void* __restrict__ W1,
                                                 unsigned short* __restrict__ h1u) {
    __shared__ __align__(16) unsigned char smem[64 * 264 * 2];   // 33792 B union
    __shared__ int flagsL[2];
    const int t = threadIdx.x;
    const void* xb = (const void*)xw;

    if (t < 64) {                              // wave 0: dtype detection
        int outliers = 0;
#pragma unroll
        for (int k = t; k < 256; k += 64) {
            int e = (xw[k] >> 7) & 0xFF;       // exponent of low bf16 half
            if (e < 100 || e > 140) outliers++;
        }
        int nz = 0;
        if (t < 32) nz = (ei[1 + 2 * t] != 0) ? 1 : 0;
#pragma unroll
        for (int off = 32; off; off >>= 1) {
            outliers += __shfl_down(outliers, off, 64);
            nz       += __shfl_down(nz, off, 64);
        }
        if (t == 0) {
            flagsL[0] = (outliers > 64) ? 1 : 0;
            flagsL[1] = (nz == 0) ? 1 : 0;
            if (blockIdx.x == 0) {             // publish for gather kernels
                flags[0] = flagsL[0];
                flags[1] = flagsL[1];
            }
        }
    }
    __syncthreads();
    const bool f32 = flagsL[0] != 0;
    const bool i64 = flagsL[1] != 0;

    if (blockIdx.x < NCH) {
        int* histL = (int*)smem;                   // [256]
        int* lbase = histL + 256;                  // [256]
        int* gbL   = lbase + 256;                  // [256]
        unsigned* recL = (unsigned*)(gbL + 256);   // [FCH]
        histL[t] = 0;
        __syncthreads();
        int dk[8], sk[8], lk[8];
        const int e0 = blockIdx.x * FCH;
#pragma unroll
        for (int k = 0; k < 8; k++) {
            int e = e0 + k * 256 + t;
            if (e < NE) {
                dk[k] = loadE(ei, e, 1, i64);
                sk[k] = loadE(ei, e, 0, i64);
                lk[k] = atomicAdd(&histL[dk[k] >> 8], 1);
            } else {
                dk[k] = -1;
            }
        }
        __syncthreads();
        const int v = histL[t];
        lbase[t] = v;
        __syncthreads();
        for (int off = 1; off < 256; off <<= 1) {
            int tmp = (t >= off) ? lbase[t - off] : 0;
            __syncthreads();
            lbase[t] += tmp;
            __syncthreads();
        }
        int excl = lbase[t] - v;
        __syncthreads();
        lbase[t] = excl;
        __syncthreads();
        // place records sorted-by-bucket in LDS, tagged with bucket in [31:24]
#pragma unroll
        for (int k = 0; k < 8; k++) {
            if (dk[k] >= 0) {
                int b = dk[k] >> 8;
                recL[lbase[b] + lk[k]] =
                    (unsigned)(sk[k] | ((dk[k] & 0xff) << 16) | (b << 24));
            }
        }
        gbL[t] = (v > 0) ? atomicAdd(&bcur[t], v) : 0;
        __syncthreads();
        // POSITION-ordered write-out: consecutive lanes -> consecutive addrs
        const int totalCnt = min(FCH, NE - e0);
        for (int pos = t; pos < totalCnt; pos += 256) {
            unsigned rec = recL[pos];
            int b = rec >> 24;
            int off = gbL[b] + (pos - lbase[b]);
            if (off < MAXB) binned[b * MAXB + off] = rec & 0xffffff;
        }
        return;
    }

    // ---------------- gemm role (bf16 output, unscaled) ----------------
    const int bid = blockIdx.x - NCH;              // 0..GB-1
    unsigned short* wt16 = (unsigned short*)smem;
    if (f32) {
        const float* wf = (const float*)W1;
        for (int i = t * 4; i < FEAT * HID; i += 1024) {
            float4 w = *(const float4*)(wf + i);
            int k = i >> 6, n0 = i & 63;
            wt16[(n0 + 0) * 264 + k] = f2bu(w.x);
            wt16[(n0 + 1) * 264 + k] = f2bu(w.y);
            wt16[(n0 + 2) * 264 + k] = f2bu(w.z);
            wt16[(n0 + 3) * 264 + k] = f2bu(w.w);
        }
    } else {
        const unsigned short* wu = (const unsigned short*)W1;
        for (int i = t * 4; i < FEAT * HID; i += 1024) {
            ushort4 w = *(const ushort4*)(wu + i);
            int k = i >> 6, n0 = i & 63;
            wt16[(n0 + 0) * 264 + k] = w.x;
            wt16[(n0 + 1) * 264 + k] = w.y;
            wt16[(n0 + 2) * 264 + k] = w.z;
            wt16[(n0 + 3) * 264 + k] = w.w;
        }
    }
    const int wv = t >> 6, lane = t & 63, l15 = lane & 15, quad = lane >> 4;
    const int gr = bid * 64 + wv * 16 + l15;
    const bool rowok = gr < NN;
    f32x4 acc[4];
#pragma unroll
    for (int nt = 0; nt < 4; nt++) acc[nt] = (f32x4){0.f, 0.f, 0.f, 0.f};
    __syncthreads();

    if (f32) {
        const float* xr = (const float*)xb + (size_t)gr * FEAT + quad * 8;
        float4 z4 = make_float4(0, 0, 0, 0);
        float4 c0 = rowok ? *(const float4*)xr : z4;
        float4 c1 = rowok ? *(const float4*)(xr + 4) : z4;
#pragma unroll
        for (int ks = 0; ks < 8; ks++) {
            float4 n0 = z4, n1 = z4;
            if (ks < 7 && rowok) {
                n0 = *(const float4*)(xr + (ks + 1) * 32);
                n1 = *(const float4*)(xr + (ks + 1) * 32 + 4);
            }
            bf16x8 a = pack8(c0, c1);
            const unsigned short* wk = wt16 + ks * 32 + quad * 8;
#pragma unroll
            for (int nt = 0; nt < 4; nt++) {
                bf16x8 b = *(const bf16x8*)(wk + (size_t)(nt * 16 + l15) * 264);
                acc[nt] = __builtin_amdgcn_mfma_f32_16x16x32_bf16(a, b, acc[nt], 0, 0, 0);
            }
            c0 = n0; c1 = n1;
        }
    } else {
        const unsigned short* xr = (const unsigned short*)xb + (size_t)gr * FEAT + quad * 8;
        bf16x8 zz = (bf16x8){0, 0, 0, 0, 0, 0, 0, 0};
        bf16x8 cur = rowok ? *(const bf16x8*)xr : zz;
#pragma unroll
        for (int ks = 0; ks < 8; ks++) {
            bf16x8 nxt = zz;
            if (ks < 7 && rowok) nxt = *(const bf16x8*)(xr + (ks + 1) * 32);
            const unsigned short* wk = wt16 + ks * 32 + quad * 8;
#pragma unroll
            for (int nt = 0; nt < 4; nt++) {
                bf16x8 b = *(const bf16x8*)(wk + (size_t)(nt * 16 + l15) * 264);
                acc[nt] = __builtin_amdgcn_mfma_f32_16x16x32_bf16(cur, b, acc[nt], 0, 0, 0);
            }
            cur = nxt;
        }
    }
    const int rbase = bid * 64 + wv * 16 + quad * 4;
#pragma unroll
    for (int r = 0; r < 4; r++) {
        int grow = rbase + r;   // < NNP always
#pragma unroll
        for (int nt = 0; nt < 4; nt++)
            h1u[(size_t)grow * HID + nt * 16 + l15] = f2bu(acc[nt][r]);
    }
}

// ---- fused rank + cnt/dinv/row_start + csr fill + h1 scale -----------------
// One block per bucket b: ranks its records, computes node degrees (LDS h[]),
// coalesced csr write, then scales h1 rows [256b, 256b+256) with dinv from h.
__global__ __launch_bounds__(256) void k_rankfillscale(const int* __restrict__ bcur,
                                                  const unsigned* __restrict__ binned,
                                                  int* __restrict__ pp,
                                                  int* __restrict__ cnt,
                                                  float* __restrict__ dinv,
                                                  int* __restrict__ row_start,
                                                  unsigned short* __restrict__ csr16,
                                                  unsigned* __restrict__ h1q,
                                                  unsigned* __restrict__ h2f) {
    __shared__ int h[256];
    __shared__ int s[256];
    __shared__ int ppL[256];
    __shared__ unsigned short csrL[MAXB];      // 9216 B
    const int t = threadIdx.x, b = blockIdx.x;
    h[t] = 0;
    if (b == 0 && t < 16) h2f[ZR * 16 + t] = 0;   // fp8 zero pad row
    __syncthreads();
    const int cntb = min(bcur[b], MAXB);
    const int base = b * MAXB;
    unsigned recA[RPT];
    int rkA[RPT];
#pragma unroll
    for (int j = 0; j < RPT; j++) {
        int pos = j * 256 + t;
        if (pos < cntb) {
            unsigned rec = binned[base + pos];
            recA[j] = rec;
            rkA[j] = atomicAdd(&h[(rec >> 16) & 0xff], 1);
        }
    }
    __syncthreads();
    // cross-bucket pp scan (partial == clamped bcur)
    int pv = (t < NC) ? min(bcur[t], MAXB) : 0;
    ppL[t] = pv;
    __syncthreads();
    for (int off = 1; off < 256; off <<= 1) {
        int tmp = (t >= off) ? ppL[t - off] : 0;
        __syncthreads();
        ppL[t] += tmp;
        __syncthreads();
    }
    int pexcl = ppL[t] - pv;
    __syncthreads();
    ppL[t] = pexcl;
    __syncthreads();
    if (b == 0) pp[t] = pexcl;
    // node-level: cnt, dinv, local row_start scan
    const int i = b * 256 + t;
    const int v = h[t];
    if (i < NN) {
        cnt[i] = v;
        dinv[i] = rsqrtf(1.0f + (float)v);     // +1 self loop
    }
    s[t] = v;
    __syncthreads();
    for (int off = 1; off < 256; off <<= 1) {
        int tmp = (t >= off) ? s[t - off] : 0;
        __syncthreads();
        s[t] += tmp;
        __syncthreads();
    }
    int excl = s[t] - v;
    if (i < NN) row_start[i] = excl;           // exclusive within chunk
    __syncthreads();
    s[t] = excl;
    __syncthreads();
    // place records into LDS csr, then stream out coalesced
#pragma unroll
    for (int j = 0; j < RPT; j++) {
        int pos = j * 256 + t;
        if (pos < cntb) {
            int lo = (recA[j] >> 16) & 0xff;
            csrL[s[lo] + rkA[j]] = (unsigned short)(recA[j] & 0xffff);
        }
    }
    __syncthreads();
    const int ppb = ppL[b];
    for (int pos = t; pos < cntb; pos += 256)
        csr16[ppb + pos] = csrL[pos];
    // scale this bucket's h1 rows: h1u = bf16(bf16(x@W1) * dinv[row])
    const int row0 = b * 256;
    for (int k = t; k < 256 * 32; k += 256) {
        int rl = k >> 5;
        int row = row0 + rl;
        if (row < NNP) {
            float dv = (row < NN) ? rsqrtf(1.0f + (float)h[rl]) : 0.f;
            unsigned u = h1q[row * 32 + (k & 31)];
            h1q[row * 32 + (k & 31)] = pack2bf(bflo(u) * dv, bfhi(u) * dv);
        }
    }
}

// ---- fused: s = sum h1'[{n}uN(n)] ; g = relu(dn*s + b1) ; h2' = dn*(g@W2) --
// R8 verbatim. h2 OUTPUT fp8 e4m3, 16-dword rows.
__global__ __launch_bounds__(256, 4) void k_gather1f(const uint2* __restrict__ h1v,
                                                  const float* __restrict__ dinv,
                                                  const int* __restrict__ row_start,
                                                  const int* __restrict__ pp,
                                                  const int* __restrict__ cnt,
                                                  const unsigned short* __restrict__ csr16,
                                                  const void* __restrict__ W2,
                                                  const void* __restrict__ b1,
                                                  const int* __restrict__ flags,
                                                  unsigned* __restrict__ h2f) {
    __shared__ __align__(16) float w2t[OUTD * 68];   // [col][k], stride 68
    __shared__ __align__(16) float gbuf[16 * 68];    // [node][k], stride 68
    __shared__ __align__(16) float obuf[16][40];     // [node][col] f32 pre-pack
    __shared__ float dns[16];
    const bool f32 = flags[0] != 0;
    const int t = threadIdx.x;
    for (int i = t; i < HID * OUTD; i += 256) {
        int c = i >> 6, k = i & 63;
        w2t[c * 68 + k] = loadF(W2, (size_t)k * OUTD + c, f32);
    }
    const int nl = t >> 4, l16 = t & 15;
    const int n = blockIdx.x * 16 + nl;      // < NN (grid exact)
    const float dn = dinv[n];
    uint2 u0 = h1v[n * 16 + l16];            // fits int: < 800016
    float a0 = bflo(u0.x), a1 = bfhi(u0.x), a2 = bflo(u0.y), a3 = bfhi(u0.y);
    float e0 = 0.f, e1 = 0.f, e2 = 0.f, e3 = 0.f;
    const int rs = row_start[n] + pp[n >> 8], c = cnt[n];
    for (int base = 0; base < c; base += 16) {
        int rem = c - base;
        int sv = (l16 < rem) ? (int)csr16[rs + base + l16] : ZR;
        uint2 b[8], d[8];
#pragma unroll
        for (int j = 0; j < 8; j++) {
            int s = __shfl(sv, j, 16);
            b[j] = h1v[(s << 4) | l16];
        }
#pragma unroll
        for (int j = 0; j < 8; j++) {
            int s = __shfl(sv, j + 8, 16);
            d[j] = h1v[(s << 4) | l16];
        }
#pragma unroll
        for (int j = 0; j < 8; j++) {
            a0 += bflo(b[j].x); a1 += bfhi(b[j].x);
            a2 += bflo(b[j].y); a3 += bfhi(b[j].y);
            e0 += bflo(d[j].x); e1 += bfhi(d[j].x);
            e2 += bflo(d[j].y); e3 += bfhi(d[j].y);
        }
    }
    int cb = 4 * l16;
    float g0 = fmaxf(dn * (a0 + e0) + loadF(b1, cb, f32), 0.f);
    float g1 = fmaxf(dn * (a1 + e1) + loadF(b1, cb + 1, f32), 0.f);
    float g2 = fmaxf(dn * (a2 + e2) + loadF(b1, cb + 2, f32), 0.f);
    float g3 = fmaxf(dn * (a3 + e3) + loadF(b1, cb + 3, f32), 0.f);
    *(float4*)(gbuf + nl * 68 + cb) = make_float4(g0, g1, g2, g3);
    if (l16 == 0) dns[nl] = dn;
    __syncthreads();
    for (int idx = t; idx < 16 * OUTD; idx += 256) {
        int node = idx / OUTD, col = idx % OUTD;
        const float4* gp = (const float4*)(gbuf + node * 68);
        const float4* wp = (const float4*)(w2t + col * 68);
        float o = 0.f;
#pragma unroll 4
        for (int k4 = 0; k4 < 16; k4++) {
            float4 a = gp[k4], b = wp[k4];
            o += a.x * b.x + a.y * b.y + a.z * b.z + a.w * b.w;
        }
        obuf[node][col] = o * dns[node];
    }
    __syncthreads();
    if (t < 160) {
        int node = t / 10, dw = t % 10;
        const float* op = obuf[node] + dw * 4;
        h2f[(blockIdx.x * 16 + node) * 16 + dw] =
            pack_fp8x4(op[0], op[1], op[2], op[3]);
    }
}

// ---- CSR gather layer 2 (fp8 h2, 1 line/row) + bias + log_softmax ----------
// R8 verbatim.
__global__ __launch_bounds__(256, 4) void k_gather2(const unsigned* __restrict__ h2f,
                                                 const float* __restrict__ dinv,
                                                 const int* __restrict__ row_start,
                                                 const int* __restrict__ pp,
                                                 const int* __restrict__ cnt,
                                                 const unsigned short* __restrict__ csr16,
                                                 const void* __restrict__ b2,
                                                 const int* __restrict__ flags,
                                                 void* __restrict__ out) {
    const bool f32 = flags[0] != 0;
    const int t = threadIdx.x;
    const int nl = t >> 4, l16 = t & 15;
    const int n = blockIdx.x * 16 + nl;      // < NN (grid exact)
    const bool act = l16 < 10;               // 10 dwords (40 fp8 cols) per row
    const float dn = dinv[n];
    const int lclamp = act ? l16 : 9;        // inactive lanes read lane-9 slot (discarded)
    float a0, a1, a2, a3;
    unpack_fp8x4(h2f[n * 16 + lclamp], a0, a1, a2, a3);   // self row
    float e0 = 0.f, e1 = 0.f, e2 = 0.f, e3 = 0.f;
    const int rs = row_start[n] + pp[n >> 8], c = cnt[n];
    for (int base = 0; base < c; base += 16) {
        int rem = c - base;
        int sv = (l16 < rem) ? (int)csr16[rs + base + l16] : ZR;
        unsigned b[8], d[8];
#pragma unroll
        for (int j = 0; j < 8; j++) {
            int s = __shfl(sv, j, 16);
            b[j] = h2f[(s << 4) + lclamp];
        }
#pragma unroll
        for (int j = 0; j < 8; j++) {
            int s = __shfl(sv, j + 8, 16);
            d[j] = h2f[(s << 4) + lclamp];
        }
#pragma unroll
        for (int j = 0; j < 8; j++) {
            float x0, x1, x2, x3, y0, y1, y2, y3;
            unpack_fp8x4(b[j], x0, x1, x2, x3);
            unpack_fp8x4(d[j], y0, y1, y2, y3);
            a0 += x0; a1 += x1; a2 += x2; a3 += x3;
            e0 += y0; e1 += y1; e2 += y2; e3 += y3;
        }
    }
    int cb = 4 * l16;
    float v0 = -3.0e38f, v1 = -3.0e38f, v2 = -3.0e38f, v3 = -3.0e38f;
    if (act) {
        v0 = dn * (a0 + e0) + loadF(b2, cb, f32);
        v1 = dn * (a1 + e1) + loadF(b2, cb + 1, f32);
        v2 = dn * (a2 + e2) + loadF(b2, cb + 2, f32);
        v3 = dn * (a3 + e3) + loadF(b2, cb + 3, f32);
    }
    float mx = fmaxf(fmaxf(v0, v1), fmaxf(v2, v3));
#pragma unroll
    for (int off = 8; off; off >>= 1) mx = fmaxf(mx, __shfl_xor(mx, off, 16));
    float ev = act ? expf(v0 - mx) + expf(v1 - mx) + expf(v2 - mx) + expf(v3 - mx) : 0.f;
#pragma unroll
    for (int off = 8; off; off >>= 1) ev += __shfl_xor(ev, off, 16);
    float lg = logf(ev);
    if (act) {
        float r0 = v0 - mx - lg, r1 = v1 - mx - lg;
        float r2 = v2 - mx - lg, r3 = v3 - mx - lg;
        if (f32) {
            *(float4*)((float*)out + (size_t)n * OUTD + cb) = make_float4(r0, r1, r2, r3);
        } else {
            ((uint2*)out)[(size_t)n * 10 + l16] = make_uint2(pack2bf(r0, r1), pack2bf(r2, r3));
        }
    }
}

extern "C" void kernel_launch(void* const* d_in, const int* in_sizes, int n_in,
                              void* d_out, int out_size, void* d_ws, size_t ws_size,
                              hipStream_t stream) {
    const void* x  = d_in[0];
    const int*  ei = (const int*)d_in[1];
    const void* W1 = d_in[2];
    const void* b1 = d_in[3];
    const void* W2 = d_in[4];
    const void* b2 = d_in[5];

    // ws layout (4-byte words):
    // flags[16] | dinv[50048] | cnt[50048] | row_start[50048] | pp[256] |
    // bcur[256] | binned uint[196*4608] | csr16 ushort[800000] |
    // h1u bf16[NNP*64] | h2f uint[NNP*16]   (~16 MB)
    float* ws        = (float*)d_ws;
    int*   flags     = (int*)ws;
    float* dinv      = ws + 16;
    int*   cnt       = (int*)(dinv + 50048);
    int*   row_start = cnt + 50048;
    int*   pp        = row_start + 50048;
    int*   bcur      = pp + 256;                                  // 256
    unsigned* binned = (unsigned*)(bcur + 256);                   // 196*4608
    unsigned short* csr16 = (unsigned short*)(binned + NBUK * MAXB);
    unsigned short* h1u   = csr16 + NE;                           // NNP*64 bf16
    unsigned* h2f = (unsigned*)(h1u + (size_t)NNP * HID);         // NNP*16 dw

    hipMemsetAsync(bcur, 0, 256 * sizeof(int), stream);
    k_bingemm <<<NCH + GB, 256, 0, stream>>>(ei, (const unsigned*)x, flags, bcur,
                                             binned, W1, h1u);
    k_rankfillscale<<<NBUK, 256, 0, stream>>>(bcur, binned, pp, cnt, dinv, row_start,
                                              csr16, (unsigned*)h1u, h2f);
    k_gather1f<<<NN / 16, 256, 0, stream>>>((const uint2*)h1u, dinv, row_start, pp, cnt,
                                            csr16, W2, b1, flags, h2f);
    k_gather2 <<<NN / 16, 256, 0, stream>>>(h2f, dinv, row_start, pp, cnt, csr16,
                                            b2, flags, d_out);
}